// Round 10
// baseline (282.834 us; speedup 1.0000x reference)
//
#include <hip/hip_runtime.h>

#define N_NODES 50000
#define N_EDGES 800000
#define DIN 256
#define DHID 128
#define DOUT 64
#define NB_SCAN 49   // ceil(50000/1024)
#define SENT N_NODES // sentinel node with zero feature row

typedef __attribute__((ext_vector_type(8))) short short8;
typedef __attribute__((ext_vector_type(4))) float f32x4;

static __device__ __forceinline__ short f2bf(float f) {
    union { float f; unsigned u; } v; v.f = f;
    unsigned r = v.u + 0x7FFFu + ((v.u >> 16) & 1u);   // RNE
    return (short)(r >> 16);
}
static __device__ __forceinline__ float bflo(unsigned p) {
    union { unsigned u; float f; } v; v.u = p << 16; return v.f;
}
static __device__ __forceinline__ float bfhi(unsigned p) {
    union { unsigned u; float f; } v; v.u = p & 0xFFFF0000u; return v.f;
}
static __device__ __forceinline__ unsigned pk(float lo, float hi) {
    return ((unsigned)(unsigned short)f2bf(lo)) |
           (((unsigned)(unsigned short)f2bf(hi)) << 16);
}

// ---------------- CSR build (rows padded to multiple of 8 with SENT) ----------------

__global__ void count_kernel(const int* __restrict__ ei, int* __restrict__ cnt,
                             int* __restrict__ loc) {
    int stride = gridDim.x * blockDim.x;
    for (int e = blockIdx.x * blockDim.x + threadIdx.x; e < N_EDGES; e += stride) {
        loc[e] = atomicAdd(&cnt[ei[N_EDGES + e]], 1);
    }
}

__global__ __launch_bounds__(1024) void bsum_kernel(const int* __restrict__ cnt,
                                                    int* __restrict__ bsum) {
    __shared__ int ws[16];
    int tid = threadIdx.x, i = blockIdx.x * 1024 + tid;
    int v = (i < N_NODES) ? cnt[i] : 0;
    v = (v + 7) & ~7;   // padded length
    #pragma unroll
    for (int off = 32; off >= 1; off >>= 1) v += __shfl_xor(v, off);
    if ((tid & 63) == 0) ws[tid >> 6] = v;
    __syncthreads();
    if (tid == 0) {
        int s = 0;
        #pragma unroll
        for (int w = 0; w < 16; ++w) s += ws[w];
        bsum[blockIdx.x] = s;
    }
}

__global__ void bscan_kernel(const int* __restrict__ bsum, int* __restrict__ bo,
                             int* __restrict__ rowptr) {
    int l = threadIdx.x;   // 64 threads
    int v = (l < NB_SCAN) ? bsum[l] : 0;
    int x = v;
    #pragma unroll
    for (int off = 1; off < 64; off <<= 1) {
        int y = __shfl_up(x, off);
        if (l >= off) x += y;
    }
    if (l < NB_SCAN) bo[l] = x - v;
    if (l == 63) rowptr[N_NODES] = x;
}

__global__ __launch_bounds__(1024) void scan_apply_kernel(const int* __restrict__ cnt,
        const int* __restrict__ bo, int* __restrict__ rowptr,
        float* __restrict__ dis, int* __restrict__ col) {
    __shared__ int wsum[16];
    int tid = threadIdx.x, i = blockIdx.x * 1024 + tid;
    int lane = tid & 63, wid = tid >> 6;
    int v = (i < N_NODES) ? cnt[i] : 0;
    int p = (v + 7) & ~7;
    int x = p;
    #pragma unroll
    for (int off = 1; off < 64; off <<= 1) {
        int y = __shfl_up(x, off);
        if (lane >= off) x += y;
    }
    if (lane == 63) wsum[wid] = x;
    __syncthreads();
    if (tid == 0) {
        int s = 0;
        #pragma unroll
        for (int w = 0; w < 16; ++w) { int t = wsum[w]; wsum[w] = s; s += t; }
    }
    __syncthreads();
    int excl = bo[blockIdx.x] + wsum[wid] + (x - p);
    if (i < N_NODES) {
        rowptr[i] = excl;
        dis[i] = rsqrtf((float)(v + 1));
        for (int q = v; q < p; ++q) col[excl + q] = SENT;   // pad slots -> zero row
    }
}

// Atomic-free placement.
__global__ void fill_kernel(const int* __restrict__ ei, const int* __restrict__ loc,
                            const int* __restrict__ rowptr, int* __restrict__ col) {
    int stride = gridDim.x * blockDim.x;
    for (int e = blockIdx.x * blockDim.x + threadIdx.x; e < N_EDGES; e += stride) {
        int s = ei[e];
        int d = ei[N_EDGES + e];
        col[rowptr[d] + loc[e]] = s;
    }
}

// ---------------- weight prep (+ sentinel-row zeroing; grid = 193 blocks) ----------------

__global__ void wprep_kernel(const float* __restrict__ W1, const float* __restrict__ Wmu,
                             const float* __restrict__ Wlv, short* __restrict__ W1b,
                             short* __restrict__ Wctb, short* __restrict__ u1b,
                             short* __restrict__ u2b) {
    int tid = blockIdx.x * blockDim.x + threadIdx.x;
    if (tid < DHID * DIN) {
        W1b[tid] = f2bf(W1[tid]);
    } else if (tid < DHID * DIN + 2 * DOUT * DHID) {
        int t = tid - DHID * DIN;
        Wctb[t] = f2bf((t < DOUT * DHID) ? Wmu[t] : Wlv[t - DOUT * DHID]);
    } else if (tid < DHID * DIN + 2 * DOUT * DHID + DHID) {
        int t = tid - (DHID * DIN + 2 * DOUT * DHID);
        u1b[(size_t)SENT * DHID + t] = 0;   // zero sentinel rows
        u2b[(size_t)SENT * DHID + t] = 0;
    }
}

// ---------------- xprep: xb[n][k] = bf16(dis[n] * x[n][k]) ----------------

__global__ __launch_bounds__(256) void xprep_kernel(const float* __restrict__ x,
        const float* __restrict__ dis, short* __restrict__ xb) {
    const int total = N_NODES * (DIN / 8);
    int stride = gridDim.x * blockDim.x;
    for (int c = blockIdx.x * blockDim.x + threadIdx.x; c < total; c += stride) {
        int row = c >> 5;            // DIN/8 = 32 chunks per row
        float d = dis[row];
        const float* src = x + (size_t)c * 8;
        float4 f0 = *(const float4*)src;
        float4 f1 = *(const float4*)(src + 4);
        short8 o;
        o[0] = f2bf(f0.x * d); o[1] = f2bf(f0.y * d);
        o[2] = f2bf(f0.z * d); o[3] = f2bf(f0.w * d);
        o[4] = f2bf(f1.x * d); o[5] = f2bf(f1.y * d);
        o[6] = f2bf(f1.z * d); o[7] = f2bf(f1.w * d);
        *(short8*)(xb + (size_t)c * 8) = o;
    }
}

// ---------------- GEMM1 (MFMA bf16): u1b = bf16(xb @ W1^T) ----------------

__global__ __launch_bounds__(256) void gemm1_mfma_kernel(const short* __restrict__ xb,
        const short* __restrict__ W1b, short* __restrict__ u1b) {
    const int lane = threadIdx.x & 63, w = threadIdx.x >> 6;
    const int l15 = lane & 15, kg = lane >> 4;
    const int nb = blockIdx.x * 64;
    const int r0 = nb + w * 16 + l15;
    const bool valid = r0 < N_NODES;
    const short* arow = xb + (size_t)r0 * DIN;

    f32x4 acc[8] = {};
    #pragma unroll
    for (int ks = 0; ks < 8; ++ks) {
        const int k0 = ks * 32 + kg * 8;
        short8 a = valid ? *(const short8*)(arow + k0)
                         : short8{0, 0, 0, 0, 0, 0, 0, 0};
        #pragma unroll
        for (int c = 0; c < 8; ++c) {
            short8 b = *(const short8*)(W1b + (size_t)(c * 16 + l15) * DIN + k0);
            acc[c] = __builtin_amdgcn_mfma_f32_16x16x32_bf16(a, b, acc[c], 0, 0, 0);
        }
    }

    const int rb = nb + w * 16 + kg * 4;
    #pragma unroll
    for (int c = 0; c < 8; ++c) {
        const int j = c * 16 + l15;
        #pragma unroll
        for (int e = 0; e < 4; ++e) {
            int r = rb + e;
            if (r < N_NODES)
                u1b[(size_t)r * DHID + j] = f2bf(acc[c][e]);
        }
    }
}

// ---------------- pull aggregation: 4 lane-groups x dwordx4 ----------------
// Wave = 4 groups of 16 lanes. Group g gathers row col[t+g], each lane 16B
// (dwordx4) => one VMEM instruction covers 4 rows (16 cache lines) -> 4x fewer
// miss-tracking entries per byte than the 4B/lane version. Cross-group combine
// via shfl_xor(16|32) once per node.

template <bool LAYER1>
__global__ __launch_bounds__(256) void pull_kernel(const int* __restrict__ rowptr,
        const int* __restrict__ col, const short* __restrict__ uin,
        const float* __restrict__ dis, const float* __restrict__ b1,
        unsigned* __restrict__ uout) {
    const int wid = threadIdx.x >> 6, lane = threadIdx.x & 63;
    const int g = lane >> 4, j = lane & 15;
    const int i = blockIdx.x * 4 + wid;
    if (i >= N_NODES) return;
    const int beg = rowptr[i], end = rowptr[i + 1];
    const uint4* __restrict__ up4 = (const uint4*)uin;   // row = 16 uint4
    float a0 = 0.f, a1 = 0.f, a2 = 0.f, a3 = 0.f;
    float a4 = 0.f, a5 = 0.f, a6 = 0.f, a7 = 0.f;
    for (int base = beg; base < end; base += 64) {
        const int rem = end - base;
        const int m = rem < 64 ? rem : 64;          // multiple of 8
        int cv = (lane < m) ? col[base + lane] : SENT;
        for (int t = 0; t < m; t += 8) {
            int c0 = __shfl(cv, t + g);
            int c1 = __shfl(cv, t + 4 + g);
            uint4 v0 = up4[(size_t)c0 * 16 + j];
            uint4 v1 = up4[(size_t)c1 * 16 + j];
            a0 += bflo(v0.x); a1 += bfhi(v0.x);
            a2 += bflo(v0.y); a3 += bfhi(v0.y);
            a4 += bflo(v0.z); a5 += bfhi(v0.z);
            a6 += bflo(v0.w); a7 += bfhi(v0.w);
            a0 += bflo(v1.x); a1 += bfhi(v1.x);
            a2 += bflo(v1.y); a3 += bfhi(v1.y);
            a4 += bflo(v1.z); a5 += bfhi(v1.z);
            a6 += bflo(v1.w); a7 += bfhi(v1.w);
        }
    }
    // combine the 4 lane-groups (each holds partial sums of the same slice j)
    a0 += __shfl_xor(a0, 16); a0 += __shfl_xor(a0, 32);
    a1 += __shfl_xor(a1, 16); a1 += __shfl_xor(a1, 32);
    a2 += __shfl_xor(a2, 16); a2 += __shfl_xor(a2, 32);
    a3 += __shfl_xor(a3, 16); a3 += __shfl_xor(a3, 32);
    a4 += __shfl_xor(a4, 16); a4 += __shfl_xor(a4, 32);
    a5 += __shfl_xor(a5, 16); a5 += __shfl_xor(a5, 32);
    a6 += __shfl_xor(a6, 16); a6 += __shfl_xor(a6, 32);
    a7 += __shfl_xor(a7, 16); a7 += __shfl_xor(a7, 32);

    const uint4 sv = up4[(size_t)i * 16 + j];
    const float di = dis[i];
    float t0 = di * (a0 + bflo(sv.x));
    float t1 = di * (a1 + bfhi(sv.x));
    float t2 = di * (a2 + bflo(sv.y));
    float t3 = di * (a3 + bfhi(sv.y));
    float t4 = di * (a4 + bflo(sv.z));
    float t5 = di * (a5 + bfhi(sv.z));
    float t6 = di * (a6 + bflo(sv.w));
    float t7 = di * (a7 + bfhi(sv.w));
    if (LAYER1) {
        float4 bl = *(const float4*)(b1 + j * 8);
        float4 bh = *(const float4*)(b1 + j * 8 + 4);
        t0 = fmaxf(t0 + bl.x, 0.f) * di;
        t1 = fmaxf(t1 + bl.y, 0.f) * di;
        t2 = fmaxf(t2 + bl.z, 0.f) * di;
        t3 = fmaxf(t3 + bl.w, 0.f) * di;
        t4 = fmaxf(t4 + bh.x, 0.f) * di;
        t5 = fmaxf(t5 + bh.y, 0.f) * di;
        t6 = fmaxf(t6 + bh.z, 0.f) * di;
        t7 = fmaxf(t7 + bh.w, 0.f) * di;
    }
    if (g == 0) {
        uint4 o;
        o.x = pk(t0, t1);
        o.y = pk(t2, t3);
        o.z = pk(t4, t5);
        o.w = pk(t6, t7);
        ((uint4*)uout)[(size_t)i * 16 + j] = o;
    }
}

// ---------------- GEMM2 (MFMA bf16): [mu|lv] = a2b @ Wctb^T + [bmu|blv] ----------------

__global__ __launch_bounds__(256) void gemm2_mfma_kernel(const short* __restrict__ a2b,
        const short* __restrict__ Wctb, const float* __restrict__ bmu,
        const float* __restrict__ blv, float* __restrict__ out) {
    const int lane = threadIdx.x & 63, w = threadIdx.x >> 6;
    const int l15 = lane & 15, kg = lane >> 4;
    const int nb = blockIdx.x * 64;
    const int r0 = nb + w * 16 + l15;
    const bool valid = r0 < N_NODES;
    const short* arow = a2b + (size_t)r0 * DHID;

    f32x4 acc[8] = {};
    #pragma unroll
    for (int ks = 0; ks < 4; ++ks) {
        const int k0 = ks * 32 + kg * 8;
        short8 a = valid ? *(const short8*)(arow + k0)
                         : short8{0, 0, 0, 0, 0, 0, 0, 0};
        #pragma unroll
        for (int c = 0; c < 8; ++c) {
            short8 b = *(const short8*)(Wctb + (size_t)(c * 16 + l15) * DHID + k0);
            acc[c] = __builtin_amdgcn_mfma_f32_16x16x32_bf16(a, b, acc[c], 0, 0, 0);
        }
    }

    float bias[8];
    #pragma unroll
    for (int c = 0; c < 8; ++c) {
        int j = c * 16 + l15;
        bias[c] = (j < DOUT) ? bmu[j] : blv[j - DOUT];
    }
    const int rb = nb + w * 16 + kg * 4;
    #pragma unroll
    for (int c = 0; c < 8; ++c) {
        const int j = c * 16 + l15;
        float* dst = (j < DOUT) ? (out + j)
                                : (out + (size_t)N_NODES * DOUT + (j - DOUT));
        #pragma unroll
        for (int e = 0; e < 4; ++e) {
            int r = rb + e;
            if (r < N_NODES)
                dst[(size_t)r * DOUT] = acc[c][e] + bias[c];
        }
    }
}

// ---------------- launcher ----------------

extern "C" void kernel_launch(void* const* d_in, const int* in_sizes, int n_in,
                              void* d_out, int out_size, void* d_ws, size_t ws_size,
                              hipStream_t stream) {
    const float* x   = (const float*)d_in[0];
    const int*   ei  = (const int*)d_in[1];
    const float* W1  = (const float*)d_in[2];
    const float* b1  = (const float*)d_in[3];
    const float* Wmu = (const float*)d_in[4];
    const float* bmu = (const float*)d_in[5];
    const float* Wlv = (const float*)d_in[6];
    const float* blv = (const float*)d_in[7];
    float* out = (float*)d_out;

    char* ws = (char*)d_ws;
    size_t off = 0;
    auto alloc = [&](size_t bytes) -> char* {
        char* p = ws + off;
        off += (bytes + 255) & ~(size_t)255;
        return p;
    };
    const size_t COL_CAP = (size_t)N_EDGES + 8 * (size_t)N_NODES + 64;  // padded CSR
    int*   cnt    = (int*)  alloc((size_t)N_NODES * 4);
    int*   rowptr = (int*)  alloc((size_t)(N_NODES + 1) * 4);
    float* dis    = (float*)alloc((size_t)N_NODES * 4);
    int*   loc    = (int*)  alloc((size_t)N_EDGES * 4);
    int*   col    = (int*)  alloc(COL_CAP * 4);
    int*   bsum   = (int*)  alloc((size_t)NB_SCAN * 4);
    int*   bo     = (int*)  alloc((size_t)NB_SCAN * 4);
    short* W1b    = (short*)alloc((size_t)DHID * DIN * 2);
    short* Wctb   = (short*)alloc((size_t)2 * DOUT * DHID * 2);
    short* xb     = (short*)alloc((size_t)N_NODES * DIN * 2);
    short* u1b    = (short*)alloc((size_t)(N_NODES + 1) * DHID * 2);  // +sentinel row
    short* u2b    = (short*)alloc((size_t)(N_NODES + 1) * DHID * 2);
    short* a2b    = u1b;   // u1b dead after pull1; reuse

    hipMemsetAsync(cnt, 0, (size_t)N_NODES * 4, stream);
    wprep_kernel<<<193, 256, 0, stream>>>(W1, Wmu, Wlv, W1b, Wctb, u1b, u2b);
    count_kernel<<<1024, 256, 0, stream>>>(ei, cnt, loc);
    bsum_kernel<<<NB_SCAN, 1024, 0, stream>>>(cnt, bsum);
    bscan_kernel<<<1, 64, 0, stream>>>(bsum, bo, rowptr);
    scan_apply_kernel<<<NB_SCAN, 1024, 0, stream>>>(cnt, bo, rowptr, dis, col);
    fill_kernel<<<1024, 256, 0, stream>>>(ei, loc, rowptr, col);
    xprep_kernel<<<2048, 256, 0, stream>>>(x, dis, xb);
    gemm1_mfma_kernel<<<(N_NODES + 63) / 64, 256, 0, stream>>>(xb, W1b, u1b);
    pull_kernel<true><<<N_NODES / 4, 256, 0, stream>>>(rowptr, col, u1b, dis, b1,
                                                       (unsigned*)u2b);
    pull_kernel<false><<<N_NODES / 4, 256, 0, stream>>>(rowptr, col, u2b, dis, nullptr,
                                                        (unsigned*)a2b);
    gemm2_mfma_kernel<<<(N_NODES + 63) / 64, 256, 0, stream>>>(a2b, Wctb, bmu, blv, out);
}

// Round 11
// 260.247 us; speedup vs baseline: 1.0868x; 1.0868x over previous
//
#include <hip/hip_runtime.h>

#define N_NODES 50000
#define N_EDGES 800000
#define DIN 256
#define DHID 128
#define DOUT 64
#define NB_SCAN 49   // ceil(50000/1024)
#define SENT N_NODES // sentinel node with zero feature row

// mega_prep role split (1024 blocks)
#define MP_XPREP_BLOCKS 640
#define MP_COUNT_BLOCKS 320
#define MP_WPREP_BLOCKS 64
// fill+gemm1 role split
#define FG_GEMM_BLOCKS 782   // ceil(50000/64)
#define FG_FILL_BLOCKS 242

typedef __attribute__((ext_vector_type(8))) short short8;
typedef __attribute__((ext_vector_type(4))) float f32x4;

static __device__ __forceinline__ short f2bf(float f) {
    union { float f; unsigned u; } v; v.f = f;
    unsigned r = v.u + 0x7FFFu + ((v.u >> 16) & 1u);   // RNE
    return (short)(r >> 16);
}
static __device__ __forceinline__ float bflo(unsigned p) {
    union { unsigned u; float f; } v; v.u = p << 16; return v.f;
}
static __device__ __forceinline__ float bfhi(unsigned p) {
    union { unsigned u; float f; } v; v.u = p & 0xFFFF0000u; return v.f;
}
static __device__ __forceinline__ unsigned pk(float lo, float hi) {
    return ((unsigned)(unsigned short)f2bf(lo)) |
           (((unsigned)(unsigned short)f2bf(hi)) << 16);
}

// ---------------- K1: mega_prep = xprep ∪ count(+loc) ∪ wprep(+sentinels) ----------------
// All three are mutually independent; block-range roles overlap them on the CUs.

__global__ __launch_bounds__(256) void mega_prep_kernel(
        const float* __restrict__ x, short* __restrict__ xb,
        const int* __restrict__ ei, int* __restrict__ cnt, int* __restrict__ loc,
        const float* __restrict__ W1, const float* __restrict__ Wmu,
        const float* __restrict__ Wlv, short* __restrict__ W1b,
        short* __restrict__ Wctb, short* __restrict__ u1b, short* __restrict__ u2b) {
    const int b = blockIdx.x;
    if (b < MP_XPREP_BLOCKS) {
        // xb[n][k] = bf16(x[n][k])  (pure convert; dis applied in gemm1 epilogue)
        const int total = N_NODES * (DIN / 8);
        const int stride = MP_XPREP_BLOCKS * 256;
        for (int c = b * 256 + threadIdx.x; c < total; c += stride) {
            const float* src = x + (size_t)c * 8;
            float4 f0 = *(const float4*)src;
            float4 f1 = *(const float4*)(src + 4);
            short8 o;
            o[0] = f2bf(f0.x); o[1] = f2bf(f0.y);
            o[2] = f2bf(f0.z); o[3] = f2bf(f0.w);
            o[4] = f2bf(f1.x); o[5] = f2bf(f1.y);
            o[6] = f2bf(f1.z); o[7] = f2bf(f1.w);
            *(short8*)(xb + (size_t)c * 8) = o;
        }
    } else if (b < MP_XPREP_BLOCKS + MP_COUNT_BLOCKS) {
        const int stride = MP_COUNT_BLOCKS * 256;
        for (int e = (b - MP_XPREP_BLOCKS) * 256 + threadIdx.x; e < N_EDGES;
             e += stride) {
            loc[e] = atomicAdd(&cnt[ei[N_EDGES + e]], 1);
        }
    } else {
        const int TOT = DHID * DIN + 2 * DOUT * DHID + DHID;
        const int stride = MP_WPREP_BLOCKS * 256;
        for (int t = (b - MP_XPREP_BLOCKS - MP_COUNT_BLOCKS) * 256 + threadIdx.x;
             t < TOT; t += stride) {
            if (t < DHID * DIN) {
                W1b[t] = f2bf(W1[t]);
            } else if (t < DHID * DIN + 2 * DOUT * DHID) {
                int u = t - DHID * DIN;
                Wctb[u] = f2bf((u < DOUT * DHID) ? Wmu[u] : Wlv[u - DOUT * DHID]);
            } else {
                int s = t - (DHID * DIN + 2 * DOUT * DHID);
                u1b[(size_t)SENT * DHID + s] = 0;   // zero sentinel rows
                u2b[(size_t)SENT * DHID + s] = 0;
            }
        }
    }
}

// ---------------- scan trio (rows padded to multiple of 8 with SENT) ----------------

__global__ __launch_bounds__(1024) void bsum_kernel(const int* __restrict__ cnt,
                                                    int* __restrict__ bsum) {
    __shared__ int ws[16];
    int tid = threadIdx.x, i = blockIdx.x * 1024 + tid;
    int v = (i < N_NODES) ? cnt[i] : 0;
    v = (v + 7) & ~7;   // padded length
    #pragma unroll
    for (int off = 32; off >= 1; off >>= 1) v += __shfl_xor(v, off);
    if ((tid & 63) == 0) ws[tid >> 6] = v;
    __syncthreads();
    if (tid == 0) {
        int s = 0;
        #pragma unroll
        for (int w = 0; w < 16; ++w) s += ws[w];
        bsum[blockIdx.x] = s;
    }
}

__global__ void bscan_kernel(const int* __restrict__ bsum, int* __restrict__ bo,
                             int* __restrict__ rowptr) {
    int l = threadIdx.x;   // 64 threads
    int v = (l < NB_SCAN) ? bsum[l] : 0;
    int x = v;
    #pragma unroll
    for (int off = 1; off < 64; off <<= 1) {
        int y = __shfl_up(x, off);
        if (l >= off) x += y;
    }
    if (l < NB_SCAN) bo[l] = x - v;
    if (l == 63) rowptr[N_NODES] = x;
}

__global__ __launch_bounds__(1024) void scan_apply_kernel(const int* __restrict__ cnt,
        const int* __restrict__ bo, int* __restrict__ rowptr,
        float* __restrict__ dis, int* __restrict__ col) {
    __shared__ int wsum[16];
    int tid = threadIdx.x, i = blockIdx.x * 1024 + tid;
    int lane = tid & 63, wid = tid >> 6;
    int v = (i < N_NODES) ? cnt[i] : 0;
    int p = (v + 7) & ~7;
    int x = p;
    #pragma unroll
    for (int off = 1; off < 64; off <<= 1) {
        int y = __shfl_up(x, off);
        if (lane >= off) x += y;
    }
    if (lane == 63) wsum[wid] = x;
    __syncthreads();
    if (tid == 0) {
        int s = 0;
        #pragma unroll
        for (int w = 0; w < 16; ++w) { int t = wsum[w]; wsum[w] = s; s += t; }
    }
    __syncthreads();
    int excl = bo[blockIdx.x] + wsum[wid] + (x - p);
    if (i < N_NODES) {
        rowptr[i] = excl;
        dis[i] = rsqrtf((float)(v + 1));
        for (int q = v; q < p; ++q) col[excl + q] = SENT;   // pad slots -> zero row
    }
}

// ---------------- K5: gemm1 ∪ fill (independent; role by block range) ----------------
// gemm1: u1b[n] = bf16(dis[n] * (xb[n] @ W1^T)); fill: atomic-free CSR placement.

__global__ __launch_bounds__(256) void fill_gemm1_kernel(
        const int* __restrict__ ei, const int* __restrict__ loc,
        const int* __restrict__ rowptr, int* __restrict__ col,
        const short* __restrict__ xb, const short* __restrict__ W1b,
        const float* __restrict__ dis, short* __restrict__ u1b) {
    const int b = blockIdx.x;
    if (b < FG_GEMM_BLOCKS) {
        const int lane = threadIdx.x & 63, w = threadIdx.x >> 6;
        const int l15 = lane & 15, kg = lane >> 4;
        const int nb = b * 64;
        const int r0 = nb + w * 16 + l15;
        const bool valid = r0 < N_NODES;
        const short* arow = xb + (size_t)r0 * DIN;

        f32x4 acc[8] = {};
        #pragma unroll
        for (int ks = 0; ks < 8; ++ks) {
            const int k0 = ks * 32 + kg * 8;
            short8 a = valid ? *(const short8*)(arow + k0)
                             : short8{0, 0, 0, 0, 0, 0, 0, 0};
            #pragma unroll
            for (int c = 0; c < 8; ++c) {
                short8 bb = *(const short8*)(W1b + (size_t)(c * 16 + l15) * DIN + k0);
                acc[c] = __builtin_amdgcn_mfma_f32_16x16x32_bf16(a, bb, acc[c], 0, 0, 0);
            }
        }

        const int rb = nb + w * 16 + kg * 4;
        float dv[4];
        #pragma unroll
        for (int e = 0; e < 4; ++e) dv[e] = (rb + e < N_NODES) ? dis[rb + e] : 0.f;
        #pragma unroll
        for (int c = 0; c < 8; ++c) {
            const int j = c * 16 + l15;
            #pragma unroll
            for (int e = 0; e < 4; ++e) {
                int r = rb + e;
                if (r < N_NODES)
                    u1b[(size_t)r * DHID + j] = f2bf(acc[c][e] * dv[e]);
            }
        }
    } else {
        const int stride = FG_FILL_BLOCKS * 256;
        for (int e = (b - FG_GEMM_BLOCKS) * 256 + threadIdx.x; e < N_EDGES;
             e += stride) {
            int s = ei[e];
            int d = ei[N_EDGES + e];
            col[rowptr[d] + loc[e]] = s;
        }
    }
}

// ---------------- pull aggregation: 4 lane-groups x dwordx4 (R10, known-good) ----------------

template <bool LAYER1>
__global__ __launch_bounds__(256) void pull_kernel(const int* __restrict__ rowptr,
        const int* __restrict__ col, const short* __restrict__ uin,
        const float* __restrict__ dis, const float* __restrict__ b1,
        unsigned* __restrict__ uout) {
    const int wid = threadIdx.x >> 6, lane = threadIdx.x & 63;
    const int g = lane >> 4, j = lane & 15;
    const int i = blockIdx.x * 4 + wid;
    if (i >= N_NODES) return;
    const int beg = rowptr[i], end = rowptr[i + 1];
    const uint4* __restrict__ up4 = (const uint4*)uin;   // row = 16 uint4
    float a0 = 0.f, a1 = 0.f, a2 = 0.f, a3 = 0.f;
    float a4 = 0.f, a5 = 0.f, a6 = 0.f, a7 = 0.f;
    for (int base = beg; base < end; base += 64) {
        const int rem = end - base;
        const int m = rem < 64 ? rem : 64;          // multiple of 8
        int cv = (lane < m) ? col[base + lane] : SENT;
        for (int t = 0; t < m; t += 8) {
            int c0 = __shfl(cv, t + g);
            int c1 = __shfl(cv, t + 4 + g);
            uint4 v0 = up4[(size_t)c0 * 16 + j];
            uint4 v1 = up4[(size_t)c1 * 16 + j];
            a0 += bflo(v0.x); a1 += bfhi(v0.x);
            a2 += bflo(v0.y); a3 += bfhi(v0.y);
            a4 += bflo(v0.z); a5 += bfhi(v0.z);
            a6 += bflo(v0.w); a7 += bfhi(v0.w);
            a0 += bflo(v1.x); a1 += bfhi(v1.x);
            a2 += bflo(v1.y); a3 += bfhi(v1.y);
            a4 += bflo(v1.z); a5 += bfhi(v1.z);
            a6 += bflo(v1.w); a7 += bfhi(v1.w);
        }
    }
    // combine the 4 lane-groups (each holds partial sums of the same slice j)
    a0 += __shfl_xor(a0, 16); a0 += __shfl_xor(a0, 32);
    a1 += __shfl_xor(a1, 16); a1 += __shfl_xor(a1, 32);
    a2 += __shfl_xor(a2, 16); a2 += __shfl_xor(a2, 32);
    a3 += __shfl_xor(a3, 16); a3 += __shfl_xor(a3, 32);
    a4 += __shfl_xor(a4, 16); a4 += __shfl_xor(a4, 32);
    a5 += __shfl_xor(a5, 16); a5 += __shfl_xor(a5, 32);
    a6 += __shfl_xor(a6, 16); a6 += __shfl_xor(a6, 32);
    a7 += __shfl_xor(a7, 16); a7 += __shfl_xor(a7, 32);

    const uint4 sv = up4[(size_t)i * 16 + j];
    const float di = dis[i];
    float t0 = di * (a0 + bflo(sv.x));
    float t1 = di * (a1 + bfhi(sv.x));
    float t2 = di * (a2 + bflo(sv.y));
    float t3 = di * (a3 + bfhi(sv.y));
    float t4 = di * (a4 + bflo(sv.z));
    float t5 = di * (a5 + bfhi(sv.z));
    float t6 = di * (a6 + bflo(sv.w));
    float t7 = di * (a7 + bfhi(sv.w));
    if (LAYER1) {
        float4 bl = *(const float4*)(b1 + j * 8);
        float4 bh = *(const float4*)(b1 + j * 8 + 4);
        t0 = fmaxf(t0 + bl.x, 0.f) * di;
        t1 = fmaxf(t1 + bl.y, 0.f) * di;
        t2 = fmaxf(t2 + bl.z, 0.f) * di;
        t3 = fmaxf(t3 + bl.w, 0.f) * di;
        t4 = fmaxf(t4 + bh.x, 0.f) * di;
        t5 = fmaxf(t5 + bh.y, 0.f) * di;
        t6 = fmaxf(t6 + bh.z, 0.f) * di;
        t7 = fmaxf(t7 + bh.w, 0.f) * di;
    }
    if (g == 0) {
        uint4 o;
        o.x = pk(t0, t1);
        o.y = pk(t2, t3);
        o.z = pk(t4, t5);
        o.w = pk(t6, t7);
        ((uint4*)uout)[(size_t)i * 16 + j] = o;
    }
}

// ---------------- GEMM2 (MFMA bf16): [mu|lv] = a2b @ Wctb^T + [bmu|blv] ----------------

__global__ __launch_bounds__(256) void gemm2_mfma_kernel(const short* __restrict__ a2b,
        const short* __restrict__ Wctb, const float* __restrict__ bmu,
        const float* __restrict__ blv, float* __restrict__ out) {
    const int lane = threadIdx.x & 63, w = threadIdx.x >> 6;
    const int l15 = lane & 15, kg = lane >> 4;
    const int nb = blockIdx.x * 64;
    const int r0 = nb + w * 16 + l15;
    const bool valid = r0 < N_NODES;
    const short* arow = a2b + (size_t)r0 * DHID;

    f32x4 acc[8] = {};
    #pragma unroll
    for (int ks = 0; ks < 4; ++ks) {
        const int k0 = ks * 32 + kg * 8;
        short8 a = valid ? *(const short8*)(arow + k0)
                         : short8{0, 0, 0, 0, 0, 0, 0, 0};
        #pragma unroll
        for (int c = 0; c < 8; ++c) {
            short8 b = *(const short8*)(Wctb + (size_t)(c * 16 + l15) * DHID + k0);
            acc[c] = __builtin_amdgcn_mfma_f32_16x16x32_bf16(a, b, acc[c], 0, 0, 0);
        }
    }

    float bias[8];
    #pragma unroll
    for (int c = 0; c < 8; ++c) {
        int j = c * 16 + l15;
        bias[c] = (j < DOUT) ? bmu[j] : blv[j - DOUT];
    }
    const int rb = nb + w * 16 + kg * 4;
    #pragma unroll
    for (int c = 0; c < 8; ++c) {
        const int j = c * 16 + l15;
        float* dst = (j < DOUT) ? (out + j)
                                : (out + (size_t)N_NODES * DOUT + (j - DOUT));
        #pragma unroll
        for (int e = 0; e < 4; ++e) {
            int r = rb + e;
            if (r < N_NODES)
                dst[(size_t)r * DOUT] = acc[c][e] + bias[c];
        }
    }
}

// ---------------- launcher ----------------

extern "C" void kernel_launch(void* const* d_in, const int* in_sizes, int n_in,
                              void* d_out, int out_size, void* d_ws, size_t ws_size,
                              hipStream_t stream) {
    const float* x   = (const float*)d_in[0];
    const int*   ei  = (const int*)d_in[1];
    const float* W1  = (const float*)d_in[2];
    const float* b1  = (const float*)d_in[3];
    const float* Wmu = (const float*)d_in[4];
    const float* bmu = (const float*)d_in[5];
    const float* Wlv = (const float*)d_in[6];
    const float* blv = (const float*)d_in[7];
    float* out = (float*)d_out;

    char* ws = (char*)d_ws;
    size_t off = 0;
    auto alloc = [&](size_t bytes) -> char* {
        char* p = ws + off;
        off += (bytes + 255) & ~(size_t)255;
        return p;
    };
    const size_t COL_CAP = (size_t)N_EDGES + 8 * (size_t)N_NODES + 64;  // padded CSR
    int*   cnt    = (int*)  alloc((size_t)N_NODES * 4);
    int*   rowptr = (int*)  alloc((size_t)(N_NODES + 1) * 4);
    float* dis    = (float*)alloc((size_t)N_NODES * 4);
    int*   loc    = (int*)  alloc((size_t)N_EDGES * 4);
    int*   col    = (int*)  alloc(COL_CAP * 4);
    int*   bsum   = (int*)  alloc((size_t)NB_SCAN * 4);
    int*   bo     = (int*)  alloc((size_t)NB_SCAN * 4);
    short* W1b    = (short*)alloc((size_t)DHID * DIN * 2);
    short* Wctb   = (short*)alloc((size_t)2 * DOUT * DHID * 2);
    short* xb     = (short*)alloc((size_t)N_NODES * DIN * 2);
    short* u1b    = (short*)alloc((size_t)(N_NODES + 1) * DHID * 2);  // +sentinel row
    short* u2b    = (short*)alloc((size_t)(N_NODES + 1) * DHID * 2);
    short* a2b    = u1b;   // u1b dead after pull1; reuse

    hipMemsetAsync(cnt, 0, (size_t)N_NODES * 4, stream);
    mega_prep_kernel<<<1024, 256, 0, stream>>>(x, xb, ei, cnt, loc, W1, Wmu, Wlv,
                                               W1b, Wctb, u1b, u2b);
    bsum_kernel<<<NB_SCAN, 1024, 0, stream>>>(cnt, bsum);
    bscan_kernel<<<1, 64, 0, stream>>>(bsum, bo, rowptr);
    scan_apply_kernel<<<NB_SCAN, 1024, 0, stream>>>(cnt, bo, rowptr, dis, col);
    fill_gemm1_kernel<<<FG_GEMM_BLOCKS + FG_FILL_BLOCKS, 256, 0, stream>>>(
        ei, loc, rowptr, col, xb, W1b, dis, u1b);
    pull_kernel<true><<<N_NODES / 4, 256, 0, stream>>>(rowptr, col, u1b, dis, b1,
                                                       (unsigned*)u2b);
    pull_kernel<false><<<N_NODES / 4, 256, 0, stream>>>(rowptr, col, u2b, dis, nullptr,
                                                        (unsigned*)a2b);
    gemm2_mfma_kernel<<<(N_NODES + 63) / 64, 256, 0, stream>>>(a2b, Wctb, bmu, blv, out);
}